// Round 8
// baseline (329.560 us; speedup 1.0000x reference)
//
#include <hip/hip_runtime.h>

using short8 = __attribute__((ext_vector_type(8))) short;
using f32x4  = __attribute__((ext_vector_type(4))) float;

#define DEV __device__ __forceinline__

#define GLBP(p) ((const __attribute__((address_space(1))) unsigned int*)(p))
#define LDSP(p) ((__attribute__((address_space(3))) unsigned int*)(p))

#define EXP2F(x) __builtin_amdgcn_exp2f(x)

// float -> bf16 round-to-nearest-even (finite inputs)
DEV unsigned short f2bf(float f) {
    unsigned int u = __float_as_uint(f);
    u += 0x7fffu + ((u >> 16) & 1u);
    return (unsigned short)(u >> 16);
}

// pack two floats into 2 bf16 (RNE), lo | hi<<16
DEV unsigned int pack2bf(float a, float b) {
    unsigned int ua = __float_as_uint(a);
    ua += 0x7fffu + ((ua >> 16) & 1u);
    unsigned int ub = __float_as_uint(b);
    ub += 0x7fffu + ((ub >> 16) & 1u);
    return (ua >> 16) | (ub & 0xffff0000u);
}

// ---------------------------------------------------------------- converts
__global__ __launch_bounds__(256) void cvt_k(const float* __restrict__ in,
                                             unsigned short* __restrict__ out, int n4) {
    int i = blockIdx.x * blockDim.x + threadIdx.x;
    int stride = gridDim.x * blockDim.x;
    for (; i < n4; i += stride) {
        float4 v = ((const float4*)in)[i];
        ushort4 o;
        o.x = f2bf(v.x); o.y = f2bf(v.y); o.z = f2bf(v.z); o.w = f2bf(v.w);
        ((ushort4*)out)[i] = o;
    }
}

// transpose + convert: in fp32 [R][C] -> out bf16 [C][R].  layerp: device scalar index
__global__ __launch_bounds__(256) void wt_k(const float* __restrict__ in,
                                            unsigned short* __restrict__ out,
                                            int R, int C,
                                            const int* __restrict__ layerp, int lstride) {
    if (layerp) in += (size_t)layerp[0] * (size_t)lstride;
    __shared__ float t[32][33];
    const int tx = threadIdx.x & 31, ty = threadIdx.x >> 5;
    const int c0 = blockIdx.x * 32, r0 = blockIdx.y * 32;
#pragma unroll
    for (int it = 0; it < 4; ++it)
        t[ty + it * 8][tx] = in[(size_t)(r0 + ty + it * 8) * C + c0 + tx];
    __syncthreads();
#pragma unroll
    for (int it = 0; it < 4; ++it)
        out[(size_t)(c0 + ty + it * 8) * R + r0 + tx] = f2bf(t[tx][ty + it * 8]);
}

// bf16 [b][2048][H*96] -> bf16 [b*H + h][96][2048]
__global__ __launch_bounds__(256) void kvt_k(const unsigned short* __restrict__ kv,
                                             unsigned short* __restrict__ kvT) {
    const int n0 = blockIdx.x * 32, d0 = blockIdx.y * 32, bh = blockIdx.z;
    const int b = bh >> 3, h = bh & 7;
    __shared__ unsigned short t[32][33];
    const int tx = threadIdx.x & 31, ty = threadIdx.x >> 5;
#pragma unroll
    for (int it = 0; it < 4; ++it)
        t[ty + it * 8][tx] = kv[(size_t)(b * 2048 + n0 + ty + it * 8) * 768 + h * 96 + d0 + tx];
    __syncthreads();
#pragma unroll
    for (int it = 0; it < 4; ++it)
        kvT[((size_t)bh * 96 + d0 + ty + it * 8) * 2048 + n0 + tx] = t[tx][ty + it * 8];
}

// ---------------------------------------------------------------- GEMM
// C[M,N] = A[M,K] * B^T  (B stored [N][K], k-contiguous).  128x128 tile, 4 waves 2x2,
// each wave 64x64 (4x4 frags of 16x16), BK=32.  LDS layout [kgroup][row128][8].
// EPI=0: write fp32.  EPI=1: add bias, scale, write bf16.
template <int EPI>
__global__ __launch_bounds__(256) void gemm128(const unsigned short* __restrict__ A,
                                               const unsigned short* __restrict__ B,
                                               void* __restrict__ out,
                                               const float* __restrict__ bias,
                                               int K, int ldc, float oscale) {
    __shared__ unsigned short smA[4096];
    __shared__ unsigned short smB[4096];
    const int tid = threadIdx.x, lane = tid & 63;
    const int l15 = lane & 15, g = lane >> 4;
    const int w = tid >> 6, wm = w >> 1, wn = w & 1;
    const int m0 = blockIdx.x * 128, n0 = blockIdx.y * 128;
    const int srow = tid >> 2, skg = tid & 3;  // staging: 64 rows x 4 kgroups per pass
    f32x4 acc[4][4] = {};
    const int nkt = K >> 5;
    for (int kt = 0; kt < nkt; ++kt) {
        const int k0 = kt << 5;
        __syncthreads();
        {
            short8 va0 = *(const short8*)(A + (size_t)(m0 + srow) * K + k0 + skg * 8);
            short8 va1 = *(const short8*)(A + (size_t)(m0 + 64 + srow) * K + k0 + skg * 8);
            short8 vb0 = *(const short8*)(B + (size_t)(n0 + srow) * K + k0 + skg * 8);
            short8 vb1 = *(const short8*)(B + (size_t)(n0 + 64 + srow) * K + k0 + skg * 8);
            *(short8*)(smA + (skg * 128 + srow) * 8) = va0;
            *(short8*)(smA + (skg * 128 + 64 + srow) * 8) = va1;
            *(short8*)(smB + (skg * 128 + srow) * 8) = vb0;
            *(short8*)(smB + (skg * 128 + 64 + srow) * 8) = vb1;
        }
        __syncthreads();
        short8 af[4], bf[4];
#pragma unroll
        for (int i = 0; i < 4; ++i)
            af[i] = *(const short8*)(smA + (g * 128 + wm * 64 + i * 16 + l15) * 8);
#pragma unroll
        for (int j = 0; j < 4; ++j)
            bf[j] = *(const short8*)(smB + (g * 128 + wn * 64 + j * 16 + l15) * 8);
#pragma unroll
        for (int i = 0; i < 4; ++i)
#pragma unroll
            for (int j = 0; j < 4; ++j)
                acc[i][j] = __builtin_amdgcn_mfma_f32_16x16x32_bf16(af[i], bf[j], acc[i][j], 0, 0, 0);
    }
#pragma unroll
    for (int j = 0; j < 4; ++j) {
        const int col = n0 + wn * 64 + j * 16 + l15;
        const float bv = (EPI == 1) ? bias[col] : 0.0f;
#pragma unroll
        for (int i = 0; i < 4; ++i)
#pragma unroll
            for (int r = 0; r < 4; ++r) {
                const int row = m0 + wm * 64 + i * 16 + g * 4 + r;
                if (EPI == 0) {
                    ((float*)out)[(size_t)row * ldc + col] = acc[i][j][r];
                } else {
                    const float v = (acc[i][j][r] + bv) * oscale;
                    ((unsigned short*)out)[(size_t)row * ldc + col] = f2bf(v);
                }
            }
    }
}

// ---------------------------------------------------------------- row norms
// one wave per 768-elem row
__global__ __launch_bounds__(256) void rownorm_k(const float* __restrict__ in,
                                                 float* __restrict__ outf,
                                                 unsigned short* __restrict__ outb) {
    const int lane = threadIdx.x & 63;
    const int row = blockIdx.x * 4 + (threadIdx.x >> 6);
    const float* p = in + (size_t)row * 768;
    float4 v[3];
    float s = 0.f;
#pragma unroll
    for (int i = 0; i < 3; ++i) {
        v[i] = ((const float4*)p)[i * 64 + lane];
        s += v[i].x * v[i].x + v[i].y * v[i].y + v[i].z * v[i].z + v[i].w * v[i].w;
    }
#pragma unroll
    for (int mask = 1; mask < 64; mask <<= 1) s += __shfl_xor(s, mask);
    const float inv = rsqrtf(s);
    float4* of = (float4*)(outf + (size_t)row * 768);
    ushort4* ob = (ushort4*)(outb + (size_t)row * 768);
#pragma unroll
    for (int i = 0; i < 3; ++i) {
        float4 q;
        q.x = v[i].x * inv; q.y = v[i].y * inv; q.z = v[i].z * inv; q.w = v[i].w * inv;
        of[i * 64 + lane] = q;
        ushort4 u;
        u.x = f2bf(q.x); u.y = f2bf(q.y); u.z = f2bf(q.z); u.w = f2bf(q.w);
        ob[i * 64 + lane] = u;
    }
}

__global__ __launch_bounds__(256) void resid_norm_k(const float* __restrict__ in,
                                                    const float* __restrict__ res,
                                                    float* __restrict__ outf) {
    const int lane = threadIdx.x & 63;
    const int row = blockIdx.x * 4 + (threadIdx.x >> 6);
    const float4* pa = (const float4*)(in + (size_t)row * 768);
    const float4* pb = (const float4*)(res + (size_t)row * 768);
    float4 v[3];
    float s = 0.f;
#pragma unroll
    for (int i = 0; i < 3; ++i) {
        float4 a = pa[i * 64 + lane];
        float4 b = pb[i * 64 + lane];
        float4 c;
        c.x = a.x + b.x; c.y = a.y + b.y; c.z = a.z + b.z; c.w = a.w + b.w;
        v[i] = c;
        s += c.x * c.x + c.y * c.y + c.z * c.z + c.w * c.w;
    }
#pragma unroll
    for (int mask = 1; mask < 64; mask <<= 1) s += __shfl_xor(s, mask);
    const float inv = rsqrtf(s);
    float4* of = (float4*)(outf + (size_t)row * 768);
#pragma unroll
    for (int i = 0; i < 3; ++i) {
        float4 q;
        q.x = v[i].x * inv; q.y = v[i].y * inv; q.z = v[i].z * inv; q.w = v[i].w * inv;
        of[i * 64 + lane] = q;
    }
}

// ---------------------------------------------------------------- fused attention
// grid = B*H*32 (XCD-swizzled); 4 waves x 16 q-rows (64 q/block).  KV chunk = 64.
// K double-buffered in LDS via global_load_lds (fragment-major, conflict-free);
// V^T loaded direct global->reg at chunk top (issue-early, consume-late in PV).
// LDS = 24KB K + 9KB P = 33KB -> 4 blocks/CU; __launch_bounds__(256,4) caps 128 VGPR.
// Swapped QK^T (q lane-local), exp2-domain softmax, defer-max, setprio on MFMA.
__global__ __launch_bounds__(256, 4) void attn_k(const unsigned short* __restrict__ Q,
                                                 const unsigned short* __restrict__ KV,
                                                 const unsigned short* __restrict__ KVT,
                                                 float* __restrict__ O) {
    __shared__ unsigned short sK[2][6144];        // 12 KiB per buffer
    __shared__ unsigned short plds[4][16][72];    // per-wave P, +8 pad
    // XCD swizzle: 128 consecutive work-ids per XCD (nwg=1024, 8 XCDs, bijective)
    const int hw = blockIdx.x;
    const int bid = (hw & 7) * 128 + (hw >> 3);
    const int qb = bid & 31, h = (bid >> 5) & 7, b = bid >> 8;
    const int tid = threadIdx.x, lane = tid & 63, w = tid >> 6;
    const int l15 = lane & 15, g = lane >> 4;
    const int q0 = qb * 64 + w * 16;
    unsigned short(*pw)[72] = plds[w];

    const unsigned short* kb = KV + (size_t)(b * 2048) * 768 + h * 96;
    const unsigned short* vb = KVT + (size_t)((b * 8 + h) * 96) * 2048;

    // Q fragments (B-operand): q = q0 + l15, d = ks*32 + g*8
    short8 aq[3];
    {
        const unsigned short* qp = Q + (size_t)(b * 2048 + q0 + l15) * 768 + h * 96 + g * 8;
#pragma unroll
        for (int ks = 0; ks < 3; ++ks) aq[ks] = *(const short8*)(qp + ks * 32);
    }
    f32x4 o[6] = {};
    float m = -__builtin_inff();
    float l = 0.f;

    // ---- K staging (3 global_load_lds per wave, 16B each) ----
    auto stage = [&](int n2, unsigned short* sKb) {
#pragma unroll
        for (int p = 0; p < 3; ++p) {
            const int ksub = p * 4 + w;
            const unsigned short* gp = kb + (size_t)(n2 + lane) * 768 + ksub * 8;
            unsigned short* lp = sKb + ksub * 64 * 8;
            __builtin_amdgcn_global_load_lds(GLBP(gp), LDSP(lp), 16, 0, 0);
        }
    };

    stage(0, sK[0]);
    __syncthreads();   // buffer 0 ready

    for (int c = 0; c < 32; ++c) {
        const int cur = c & 1;
        const unsigned short* sKb = sK[cur];
        const int n2 = c * 64;
        if (c < 31) stage(n2 + 64, sK[cur ^ 1]);

        // V^T for this chunk: issue early, consume in PV (~whole chunk of cover)
        short8 vv[12];
#pragma unroll
        for (int half = 0; half < 2; ++half)
#pragma unroll
            for (int dt = 0; dt < 6; ++dt)
                vv[half * 6 + dt] = *(const short8*)(vb + (size_t)(dt * 16 + l15) * 2048 + n2 + half * 32 + g * 8);

        // ---- QK^T (swapped): S^T[kv][q], q = l15 lane-local ----
        f32x4 s[4];
        __builtin_amdgcn_s_setprio(1);
#pragma unroll
        for (int t = 0; t < 4; ++t) {
            short8 k0 = *(const short8*)(sKb + ((0 + g) * 64 + t * 16 + l15) * 8);
            short8 k1 = *(const short8*)(sKb + ((4 + g) * 64 + t * 16 + l15) * 8);
            short8 k2 = *(const short8*)(sKb + ((8 + g) * 64 + t * 16 + l15) * 8);
            f32x4 a = {};
            a = __builtin_amdgcn_mfma_f32_16x16x32_bf16(k0, aq[0], a, 0, 0, 0);
            a = __builtin_amdgcn_mfma_f32_16x16x32_bf16(k1, aq[1], a, 0, 0, 0);
            a = __builtin_amdgcn_mfma_f32_16x16x32_bf16(k2, aq[2], a, 0, 0, 0);
            s[t] = a;
        }
        __builtin_amdgcn_s_setprio(0);
        // ---- softmax (exp2 domain) ----
        {
            float cm = s[0][0];
#pragma unroll
            for (int t = 0; t < 4; ++t)
#pragma unroll
                for (int r = 0; r < 4; ++r)
                    if (t | r) cm = fmaxf(cm, s[t][r]);
            cm = fmaxf(cm, __shfl_xor(cm, 16));
            cm = fmaxf(cm, __shfl_xor(cm, 32));
            if (!__all(cm <= m + 11.5416f)) {     // 8 nats in log2 units
                const float nm = fmaxf(m, cm);
                const float al = EXP2F(m - nm);
                m = nm;
                l *= al;
                float alb[4];
#pragma unroll
                for (int r = 0; r < 4; ++r) alb[r] = __shfl(al, g * 4 + r);
#pragma unroll
                for (int dt = 0; dt < 6; ++dt)
#pragma unroll
                    for (int r = 0; r < 4; ++r) o[dt][r] *= alb[r];
            }
            float ls = 0.f;
#pragma unroll
            for (int t = 0; t < 4; ++t)
#pragma unroll
                for (int r = 0; r < 4; ++r) {
                    const float p = EXP2F(s[t][r] - m);
                    s[t][r] = p;
                    ls += p;
                }
            ls += __shfl_xor(ls, 16);
            ls += __shfl_xor(ls, 32);
            l += ls;
            // write P^T -> P[q][kv] (one ds_write_b64 per t)
#pragma unroll
            for (int t = 0; t < 4; ++t) {
                uint2 pk;
                pk.x = pack2bf(s[t][0], s[t][1]);
                pk.y = pack2bf(s[t][2], s[t][3]);
                *(uint2*)&pw[l15][t * 16 + g * 4] = pk;
            }
        }
        // ---- PV: O[q][d] += P[q][kv] * V^T[d][kv] ----
        __builtin_amdgcn_s_setprio(1);
#pragma unroll
        for (int half = 0; half < 2; ++half) {
            short8 pa = *(const short8*)&pw[l15][half * 32 + g * 8];
#pragma unroll
            for (int dt = 0; dt < 6; ++dt)
                o[dt] = __builtin_amdgcn_mfma_f32_16x16x32_bf16(pa, vv[half * 6 + dt], o[dt], 0, 0, 0);
        }
        __builtin_amdgcn_s_setprio(0);
        __syncthreads();   // drains staging vmcnt; next K buffer ready, this one free
    }
    // epilogue: normalize rows (l lives at lane l15 == q&15; o rows are q = g*4+r)
#pragma unroll
    for (int r = 0; r < 4; ++r) {
        const float inv = 1.0f / __shfl(l, g * 4 + r);
        float* op = O + (size_t)(b * 2048 + q0 + g * 4 + r) * 768 + h * 96 + l15;
#pragma unroll
        for (int dt = 0; dt < 6; ++dt) op[dt * 16] = o[dt][r] * inv;
    }
}

// ---------------------------------------------------------------- launch
// SCALE * log2(e): softmax runs in exp2 domain
#define SCALE_F 0.05205877254075156f

extern "C" void kernel_launch(void* const* d_in, const int* in_sizes, int n_in,
                              void* d_out, int out_size, void* d_ws, size_t ws_size,
                              hipStream_t stream) {
    const float* Ft = (const float*)d_in[0];   // [4,2048,768]
    const float* Fs = (const float*)d_in[1];   // [4,2048,1024]
    const float* Wl = (const float*)d_in[2];   // [4,1024,768]
    const float* Wq = (const float*)d_in[3];   // [768,768]
    const float* bq = (const float*)d_in[4];   // [768]
    const int* layer = (const int*)d_in[5];    // scalar

    float* out0 = (float*)d_out;               // F_t_a [4,2048,768]
    float* out1 = out0 + 6291456;              // F_s_p [4,2048,768]

    char* ws = (char*)d_ws;
    unsigned short* wsFs  = (unsigned short*)(ws);              // 16,777,216 B (reused for q after gemm1)
    unsigned short* wsFt  = (unsigned short*)(ws + 16777216);   // 12,582,912
    unsigned short* wsWlt = (unsigned short*)(ws + 29360128);   //  1,572,864
    unsigned short* wsWqt = (unsigned short*)(ws + 30932992);   //  1,179,648
    unsigned short* wsKV  = (unsigned short*)(ws + 32112640);   // 12,582,912
    unsigned short* wsKVT = (unsigned short*)(ws + 44695552);   // 12,582,912
    float*          wsTmp = (float*)(ws + 57278464);            // 25,165,824 (end ~82.4 MB)
    unsigned short* wsQ   = wsFs;

    cvt_k<<<2048, 256, 0, stream>>>(Fs, wsFs, 8388608 / 4);
    cvt_k<<<2048, 256, 0, stream>>>(Ft, wsFt, 6291456 / 4);
    wt_k<<<dim3(768 / 32, 1024 / 32), 256, 0, stream>>>(Wl, wsWlt, 1024, 768, layer, 1024 * 768);
    wt_k<<<dim3(768 / 32, 768 / 32), 256, 0, stream>>>(Wq, wsWqt, 768, 768, nullptr, 0);
    // proj = F_s @ W_lin[layer]  (fp32 to wsTmp)
    gemm128<0><<<dim3(64, 6), 256, 0, stream>>>(wsFs, wsWlt, (void*)wsTmp, nullptr, 1024, 768, 1.0f);
    // F_s_p = normalize(proj) -> out1 (fp32) + wsKV (bf16)
    rownorm_k<<<2048, 256, 0, stream>>>(wsTmp, out1, wsKV);
    kvt_k<<<dim3(64, 3, 32), 256, 0, stream>>>(wsKV, wsKVT);
    // q = (F_t @ W_q + b_q) * SCALE * log2e  (bf16 to wsQ)
    gemm128<1><<<dim3(64, 6), 256, 0, stream>>>(wsFt, wsWqt, (void*)wsQ, bq, 768, 768, SCALE_F);
    // attention -> wsTmp (fp32, pre-residual)
    attn_k<<<1024, 256, 0, stream>>>(wsQ, wsKV, wsKVT, wsTmp);
    // out0 = normalize(attn_out + F_t)
    resid_norm_k<<<2048, 256, 0, stream>>>(wsTmp, Ft, out0);
}

// Round 9
// 196.755 us; speedup vs baseline: 1.6750x; 1.6750x over previous
//
#include <hip/hip_runtime.h>

using short8 = __attribute__((ext_vector_type(8))) short;
using f32x4  = __attribute__((ext_vector_type(4))) float;

#define DEV __device__ __forceinline__

#define GLBP(p) ((const __attribute__((address_space(1))) unsigned int*)(p))
#define LDSP(p) ((__attribute__((address_space(3))) unsigned int*)(p))

#define EXP2F(x) __builtin_amdgcn_exp2f(x)

// float -> bf16 round-to-nearest-even (finite inputs)
DEV unsigned short f2bf(float f) {
    unsigned int u = __float_as_uint(f);
    u += 0x7fffu + ((u >> 16) & 1u);
    return (unsigned short)(u >> 16);
}

// pack two floats into 2 bf16 (RNE), lo | hi<<16
DEV unsigned int pack2bf(float a, float b) {
    unsigned int ua = __float_as_uint(a);
    ua += 0x7fffu + ((ua >> 16) & 1u);
    unsigned int ub = __float_as_uint(b);
    ub += 0x7fffu + ((ub >> 16) & 1u);
    return (ua >> 16) | (ub & 0xffff0000u);
}

// ---------------------------------------------------------------- converts
__global__ __launch_bounds__(256) void cvt_k(const float* __restrict__ in,
                                             unsigned short* __restrict__ out, int n4) {
    int i = blockIdx.x * blockDim.x + threadIdx.x;
    int stride = gridDim.x * blockDim.x;
    for (; i < n4; i += stride) {
        float4 v = ((const float4*)in)[i];
        ushort4 o;
        o.x = f2bf(v.x); o.y = f2bf(v.y); o.z = f2bf(v.z); o.w = f2bf(v.w);
        ((ushort4*)out)[i] = o;
    }
}

// transpose + convert: in fp32 [R][C] -> out bf16 [C][R].  layerp: device scalar index
__global__ __launch_bounds__(256) void wt_k(const float* __restrict__ in,
                                            unsigned short* __restrict__ out,
                                            int R, int C,
                                            const int* __restrict__ layerp, int lstride) {
    if (layerp) in += (size_t)layerp[0] * (size_t)lstride;
    __shared__ float t[32][33];
    const int tx = threadIdx.x & 31, ty = threadIdx.x >> 5;
    const int c0 = blockIdx.x * 32, r0 = blockIdx.y * 32;
#pragma unroll
    for (int it = 0; it < 4; ++it)
        t[ty + it * 8][tx] = in[(size_t)(r0 + ty + it * 8) * C + c0 + tx];
    __syncthreads();
#pragma unroll
    for (int it = 0; it < 4; ++it)
        out[(size_t)(c0 + ty + it * 8) * R + r0 + tx] = f2bf(t[tx][ty + it * 8]);
}

// bf16 [b][2048][H*96] -> bf16 [b*H + h][96][2048]
__global__ __launch_bounds__(256) void kvt_k(const unsigned short* __restrict__ kv,
                                             unsigned short* __restrict__ kvT) {
    const int n0 = blockIdx.x * 32, d0 = blockIdx.y * 32, bh = blockIdx.z;
    const int b = bh >> 3, h = bh & 7;
    __shared__ unsigned short t[32][33];
    const int tx = threadIdx.x & 31, ty = threadIdx.x >> 5;
#pragma unroll
    for (int it = 0; it < 4; ++it)
        t[ty + it * 8][tx] = kv[(size_t)(b * 2048 + n0 + ty + it * 8) * 768 + h * 96 + d0 + tx];
    __syncthreads();
#pragma unroll
    for (int it = 0; it < 4; ++it)
        kvT[((size_t)bh * 96 + d0 + ty + it * 8) * 2048 + n0 + tx] = t[tx][ty + it * 8];
}

// ---------------------------------------------------------------- GEMM
// C[M,N] = A[M,K] * B^T  (B stored [N][K], k-contiguous).  128x128 tile, 4 waves 2x2,
// each wave 64x64 (4x4 frags of 16x16), BK=32.  LDS layout [kgroup][row128][8].
// EPI=0: write fp32.  EPI=1: add bias, scale, write bf16.
template <int EPI>
__global__ __launch_bounds__(256) void gemm128(const unsigned short* __restrict__ A,
                                               const unsigned short* __restrict__ B,
                                               void* __restrict__ out,
                                               const float* __restrict__ bias,
                                               int K, int ldc, float oscale) {
    __shared__ unsigned short smA[4096];
    __shared__ unsigned short smB[4096];
    const int tid = threadIdx.x, lane = tid & 63;
    const int l15 = lane & 15, g = lane >> 4;
    const int w = tid >> 6, wm = w >> 1, wn = w & 1;
    const int m0 = blockIdx.x * 128, n0 = blockIdx.y * 128;
    const int srow = tid >> 2, skg = tid & 3;  // staging: 64 rows x 4 kgroups per pass
    f32x4 acc[4][4] = {};
    const int nkt = K >> 5;
    for (int kt = 0; kt < nkt; ++kt) {
        const int k0 = kt << 5;
        __syncthreads();
        {
            short8 va0 = *(const short8*)(A + (size_t)(m0 + srow) * K + k0 + skg * 8);
            short8 va1 = *(const short8*)(A + (size_t)(m0 + 64 + srow) * K + k0 + skg * 8);
            short8 vb0 = *(const short8*)(B + (size_t)(n0 + srow) * K + k0 + skg * 8);
            short8 vb1 = *(const short8*)(B + (size_t)(n0 + 64 + srow) * K + k0 + skg * 8);
            *(short8*)(smA + (skg * 128 + srow) * 8) = va0;
            *(short8*)(smA + (skg * 128 + 64 + srow) * 8) = va1;
            *(short8*)(smB + (skg * 128 + srow) * 8) = vb0;
            *(short8*)(smB + (skg * 128 + 64 + srow) * 8) = vb1;
        }
        __syncthreads();
        short8 af[4], bf[4];
#pragma unroll
        for (int i = 0; i < 4; ++i)
            af[i] = *(const short8*)(smA + (g * 128 + wm * 64 + i * 16 + l15) * 8);
#pragma unroll
        for (int j = 0; j < 4; ++j)
            bf[j] = *(const short8*)(smB + (g * 128 + wn * 64 + j * 16 + l15) * 8);
#pragma unroll
        for (int i = 0; i < 4; ++i)
#pragma unroll
            for (int j = 0; j < 4; ++j)
                acc[i][j] = __builtin_amdgcn_mfma_f32_16x16x32_bf16(af[i], bf[j], acc[i][j], 0, 0, 0);
    }
#pragma unroll
    for (int j = 0; j < 4; ++j) {
        const int col = n0 + wn * 64 + j * 16 + l15;
        const float bv = (EPI == 1) ? bias[col] : 0.0f;
#pragma unroll
        for (int i = 0; i < 4; ++i)
#pragma unroll
            for (int r = 0; r < 4; ++r) {
                const int row = m0 + wm * 64 + i * 16 + g * 4 + r;
                if (EPI == 0) {
                    ((float*)out)[(size_t)row * ldc + col] = acc[i][j][r];
                } else {
                    const float v = (acc[i][j][r] + bv) * oscale;
                    ((unsigned short*)out)[(size_t)row * ldc + col] = f2bf(v);
                }
            }
    }
}

// ---------------------------------------------------------------- row norms
// one wave per 768-elem row
__global__ __launch_bounds__(256) void rownorm_k(const float* __restrict__ in,
                                                 float* __restrict__ outf,
                                                 unsigned short* __restrict__ outb) {
    const int lane = threadIdx.x & 63;
    const int row = blockIdx.x * 4 + (threadIdx.x >> 6);
    const float* p = in + (size_t)row * 768;
    float4 v[3];
    float s = 0.f;
#pragma unroll
    for (int i = 0; i < 3; ++i) {
        v[i] = ((const float4*)p)[i * 64 + lane];
        s += v[i].x * v[i].x + v[i].y * v[i].y + v[i].z * v[i].z + v[i].w * v[i].w;
    }
#pragma unroll
    for (int mask = 1; mask < 64; mask <<= 1) s += __shfl_xor(s, mask);
    const float inv = rsqrtf(s);
    float4* of = (float4*)(outf + (size_t)row * 768);
    ushort4* ob = (ushort4*)(outb + (size_t)row * 768);
#pragma unroll
    for (int i = 0; i < 3; ++i) {
        float4 q;
        q.x = v[i].x * inv; q.y = v[i].y * inv; q.z = v[i].z * inv; q.w = v[i].w * inv;
        of[i * 64 + lane] = q;
        ushort4 u;
        u.x = f2bf(q.x); u.y = f2bf(q.y); u.z = f2bf(q.z); u.w = f2bf(q.w);
        ob[i * 64 + lane] = u;
    }
}

__global__ __launch_bounds__(256) void resid_norm_k(const float* __restrict__ in,
                                                    const float* __restrict__ res,
                                                    float* __restrict__ outf) {
    const int lane = threadIdx.x & 63;
    const int row = blockIdx.x * 4 + (threadIdx.x >> 6);
    const float4* pa = (const float4*)(in + (size_t)row * 768);
    const float4* pb = (const float4*)(res + (size_t)row * 768);
    float4 v[3];
    float s = 0.f;
#pragma unroll
    for (int i = 0; i < 3; ++i) {
        float4 a = pa[i * 64 + lane];
        float4 b = pb[i * 64 + lane];
        float4 c;
        c.x = a.x + b.x; c.y = a.y + b.y; c.z = a.z + b.z; c.w = a.w + b.w;
        v[i] = c;
        s += c.x * c.x + c.y * c.y + c.z * c.z + c.w * c.w;
    }
#pragma unroll
    for (int mask = 1; mask < 64; mask <<= 1) s += __shfl_xor(s, mask);
    const float inv = rsqrtf(s);
    float4* of = (float4*)(outf + (size_t)row * 768);
#pragma unroll
    for (int i = 0; i < 3; ++i) {
        float4 q;
        q.x = v[i].x * inv; q.y = v[i].y * inv; q.z = v[i].z * inv; q.w = v[i].w * inv;
        of[i * 64 + lane] = q;
    }
}

// ---------------------------------------------------------------- fused attention
// grid = B*H*16 (XCD-swizzled); 4 waves x 32 q-rows (128 q/block).  KV chunk = 64,
// K and V^T double-buffered in LDS via global_load_lds, fragment-major layout:
//   K:  cell(ksub 0..11, r 0..63)  at (ksub*64 + r)*16B   -> holds K[n2+r][ksub*8..+8]
//   V^T:cell(kvsub 0..7, d 0..95)  at (kvsub*96 + d)*16B  -> holds VT[d][n2+kvsub*8..+8]
// XCD swizzle: each XCD owns 64 consecutive bids = 1 batch x 4 heads -> 3.1MB K+V
// resident in its 4MB L2 (R8 measured: FETCH 104MB -> 18MB).
// Swapped QK^T (q lane-local), exp2-domain softmax, defer-max, setprio on MFMA.
__global__ __launch_bounds__(256) void attn_k(const unsigned short* __restrict__ Q,
                                              const unsigned short* __restrict__ KV,
                                              const unsigned short* __restrict__ KVT,
                                              float* __restrict__ O) {
    __shared__ unsigned short sK[2][6144];   // 12 KiB per buffer
    __shared__ unsigned short sV[2][6144];   // 12 KiB per buffer
    __shared__ unsigned short plds[4][32][72];
    // bijective XCD swizzle for nwg=512: XCD x gets bids [x*64, (x+1)*64)
    const int hw = blockIdx.x;
    const int bid = (hw & 7) * 64 + (hw >> 3);
    const int qb = bid & 15, h = (bid >> 4) & 7, b = bid >> 7;
    const int tid = threadIdx.x, lane = tid & 63, w = tid >> 6;
    const int l15 = lane & 15, g = lane >> 4;
    const int q0 = qb * 128 + w * 32;
    unsigned short(*pw)[72] = plds[w];

    const unsigned short* kb = KV + (size_t)(b * 2048) * 768 + h * 96;
    const unsigned short* vb = KVT + (size_t)((b * 8 + h) * 96) * 2048;

    // Q fragments (B-operand): q = q0 + mi*16 + l15, d = ks*32 + g*8
    short8 aq[2][3];
#pragma unroll
    for (int mi = 0; mi < 2; ++mi) {
        const unsigned short* qp = Q + (size_t)(b * 2048 + q0 + mi * 16 + l15) * 768 + h * 96 + g * 8;
#pragma unroll
        for (int ks = 0; ks < 3; ++ks) aq[mi][ks] = *(const short8*)(qp + ks * 32);
    }
    f32x4 o[2][6] = {};
    float m[2] = {-__builtin_inff(), -__builtin_inff()};
    float l[2] = {0.f, 0.f};

    // ---- staging helper (6 global_load_lds per wave, 16B each) ----
    auto stage = [&](int n2, unsigned short* sKb, unsigned short* sVb) {
#pragma unroll
        for (int p = 0; p < 3; ++p) {
            const int ksub = p * 4 + w;
            const unsigned short* gp = kb + (size_t)(n2 + lane) * 768 + ksub * 8;
            unsigned short* lp = sKb + ksub * 64 * 8;
            __builtin_amdgcn_global_load_lds(GLBP(gp), LDSP(lp), 16, 0, 0);
        }
#pragma unroll
        for (int p = 0; p < 3; ++p) {
            const int i = (p * 4 + w) * 64 + lane;
            const int kvsub = i / 96;
            const int d = i - kvsub * 96;
            const unsigned short* gp = vb + (size_t)d * 2048 + n2 + kvsub * 8;
            unsigned short* lp = sVb + (p * 4 + w) * 64 * 8;
            __builtin_amdgcn_global_load_lds(GLBP(gp), LDSP(lp), 16, 0, 0);
        }
    };

    stage(0, sK[0], sV[0]);
    __syncthreads();   // drains vmcnt+lgkmcnt, buffer 0 ready

    for (int c = 0; c < 32; ++c) {
        const int cur = c & 1;
        const unsigned short* sKb = sK[cur];
        const unsigned short* sVb = sV[cur];
        if (c < 31) stage((c + 1) * 64, sK[cur ^ 1], sV[cur ^ 1]);

        // ---- QK^T (swapped): S^T[kv][q], q = mi*16 + l15 lane-local ----
        f32x4 s[2][4];
        __builtin_amdgcn_s_setprio(1);
#pragma unroll
        for (int t = 0; t < 4; ++t) {
            short8 k0 = *(const short8*)(sKb + ((0 + g) * 64 + t * 16 + l15) * 8);
            short8 k1 = *(const short8*)(sKb + ((4 + g) * 64 + t * 16 + l15) * 8);
            short8 k2 = *(const short8*)(sKb + ((8 + g) * 64 + t * 16 + l15) * 8);
#pragma unroll
            for (int mi = 0; mi < 2; ++mi) {
                f32x4 a = {};
                a = __builtin_amdgcn_mfma_f32_16x16x32_bf16(k0, aq[mi][0], a, 0, 0, 0);
                a = __builtin_amdgcn_mfma_f32_16x16x32_bf16(k1, aq[mi][1], a, 0, 0, 0);
                a = __builtin_amdgcn_mfma_f32_16x16x32_bf16(k2, aq[mi][2], a, 0, 0, 0);
                s[mi][t] = a;
            }
        }
        __builtin_amdgcn_s_setprio(0);
        // ---- softmax (exp2 domain) ----
#pragma unroll
        for (int mi = 0; mi < 2; ++mi) {
            float cm = s[mi][0][0];
#pragma unroll
            for (int t = 0; t < 4; ++t)
#pragma unroll
                for (int r = 0; r < 4; ++r)
                    if (t | r) cm = fmaxf(cm, s[mi][t][r]);
            cm = fmaxf(cm, __shfl_xor(cm, 16));
            cm = fmaxf(cm, __shfl_xor(cm, 32));
            if (!__all(cm <= m[mi] + 11.5416f)) {     // 8 nats in log2 units
                const float nm = fmaxf(m[mi], cm);
                const float al = EXP2F(m[mi] - nm);
                m[mi] = nm;
                l[mi] *= al;
                float alb[4];
#pragma unroll
                for (int r = 0; r < 4; ++r) alb[r] = __shfl(al, g * 4 + r);
#pragma unroll
                for (int dt = 0; dt < 6; ++dt)
#pragma unroll
                    for (int r = 0; r < 4; ++r) o[mi][dt][r] *= alb[r];
            }
            float ls = 0.f;
#pragma unroll
            for (int t = 0; t < 4; ++t)
#pragma unroll
                for (int r = 0; r < 4; ++r) {
                    const float p = EXP2F(s[mi][t][r] - m[mi]);
                    s[mi][t][r] = p;
                    ls += p;
                }
            ls += __shfl_xor(ls, 16);
            ls += __shfl_xor(ls, 32);
            l[mi] += ls;
            // write P^T -> P[q][kv] (one ds_write_b64 per (mi,t))
#pragma unroll
            for (int t = 0; t < 4; ++t) {
                uint2 pk;
                pk.x = pack2bf(s[mi][t][0], s[mi][t][1]);
                pk.y = pack2bf(s[mi][t][2], s[mi][t][3]);
                *(uint2*)&pw[mi * 16 + l15][t * 16 + g * 4] = pk;
            }
        }
        // ---- PV: O[q][d] += P[q][kv] * V^T[d][kv] ----
        __builtin_amdgcn_s_setprio(1);
#pragma unroll
        for (int half = 0; half < 2; ++half) {
            short8 pa[2];
#pragma unroll
            for (int mi = 0; mi < 2; ++mi)
                pa[mi] = *(const short8*)&pw[mi * 16 + l15][half * 32 + g * 8];
#pragma unroll
            for (int dt = 0; dt < 6; ++dt) {
                short8 bv = *(const short8*)(sVb + ((half * 4 + g) * 96 + dt * 16 + l15) * 8);
#pragma unroll
                for (int mi = 0; mi < 2; ++mi)
                    o[mi][dt] = __builtin_amdgcn_mfma_f32_16x16x32_bf16(pa[mi], bv, o[mi][dt], 0, 0, 0);
            }
        }
        __builtin_amdgcn_s_setprio(0);
        __syncthreads();   // drains staging vmcnt; next buffer ready, this buffer free
    }
    // epilogue: normalize rows (l lives at lane l15 == q&15; o rows are q = g*4+r)
#pragma unroll
    for (int mi = 0; mi < 2; ++mi)
#pragma unroll
        for (int r = 0; r < 4; ++r) {
            const float inv = 1.0f / __shfl(l[mi], g * 4 + r);
            float* op = O + (size_t)(b * 2048 + q0 + mi * 16 + g * 4 + r) * 768 + h * 96 + l15;
#pragma unroll
            for (int dt = 0; dt < 6; ++dt) op[dt * 16] = o[mi][dt][r] * inv;
        }
}

// ---------------------------------------------------------------- launch
// SCALE * log2(e): softmax runs in exp2 domain
#define SCALE_F 0.05205877254075156f

extern "C" void kernel_launch(void* const* d_in, const int* in_sizes, int n_in,
                              void* d_out, int out_size, void* d_ws, size_t ws_size,
                              hipStream_t stream) {
    const float* Ft = (const float*)d_in[0];   // [4,2048,768]
    const float* Fs = (const float*)d_in[1];   // [4,2048,1024]
    const float* Wl = (const float*)d_in[2];   // [4,1024,768]
    const float* Wq = (const float*)d_in[3];   // [768,768]
    const float* bq = (const float*)d_in[4];   // [768]
    const int* layer = (const int*)d_in[5];    // scalar

    float* out0 = (float*)d_out;               // F_t_a [4,2048,768]
    float* out1 = out0 + 6291456;              // F_s_p [4,2048,768]

    char* ws = (char*)d_ws;
    unsigned short* wsFs  = (unsigned short*)(ws);              // 16,777,216 B (reused for q after gemm1)
    unsigned short* wsFt  = (unsigned short*)(ws + 16777216);   // 12,582,912
    unsigned short* wsWlt = (unsigned short*)(ws + 29360128);   //  1,572,864
    unsigned short* wsWqt = (unsigned short*)(ws + 30932992);   //  1,179,648
    unsigned short* wsKV  = (unsigned short*)(ws + 32112640);   // 12,582,912
    unsigned short* wsKVT = (unsigned short*)(ws + 44695552);   // 12,582,912
    float*          wsTmp = (float*)(ws + 57278464);            // 25,165,824 (end ~82.4 MB)
    unsigned short* wsQ   = wsFs;

    cvt_k<<<2048, 256, 0, stream>>>(Fs, wsFs, 8388608 / 4);
    cvt_k<<<2048, 256, 0, stream>>>(Ft, wsFt, 6291456 / 4);
    wt_k<<<dim3(768 / 32, 1024 / 32), 256, 0, stream>>>(Wl, wsWlt, 1024, 768, layer, 1024 * 768);
    wt_k<<<dim3(768 / 32, 768 / 32), 256, 0, stream>>>(Wq, wsWqt, 768, 768, nullptr, 0);
    // proj = F_s @ W_lin[layer]  (fp32 to wsTmp)
    gemm128<0><<<dim3(64, 6), 256, 0, stream>>>(wsFs, wsWlt, (void*)wsTmp, nullptr, 1024, 768, 1.0f);
    // F_s_p = normalize(proj) -> out1 (fp32) + wsKV (bf16)
    rownorm_k<<<2048, 256, 0, stream>>>(wsTmp, out1, wsKV);
    kvt_k<<<dim3(64, 3, 32), 256, 0, stream>>>(wsKV, wsKVT);
    // q = (F_t @ W_q + b_q) * SCALE * log2e  (bf16 to wsQ)
    gemm128<1><<<dim3(64, 6), 256, 0, stream>>>(wsFt, wsWqt, (void*)wsQ, bq, 768, 768, SCALE_F);
    // attention -> wsTmp (fp32, pre-residual)
    attn_k<<<512, 256, 0, stream>>>(wsQ, wsKV, wsKVT, wsTmp);
    // out0 = normalize(attn_out + F_t)
    resid_norm_k<<<2048, 256, 0, stream>>>(wsTmp, Ft, out0);
}